// Round 1
// baseline (116.617 us; speedup 1.0000x reference)
//
#include <hip/hip_runtime.h>
#include <math.h>

// Problem shape (fixed by setup_inputs)
#define Bb 2
#define Vv 3
#define NI (Bb*(Vv-1))   // 4 (b, view-pair) combos
#define Hh 64
#define Ww 64
#define Nn (Hh*Ww)       // 4096 points per cloud
#define NBLK 16          // row-blocks per direction (16*256 = 4096 rows)
#define NDIR (NI*4)      // 16 direction computations
#define TILE 512
#define BIGF 1000000000.0f

// ws layout (float offsets)
#define OFF_KINV 0                         // B*9
#define OFF_TM   32                        // per (b,i): T_t2r[16], T_r2t[16]
#define OFF_NA   (OFF_TM + NI*32)          // B*V mask sums (maxed with 1)
#define OFF_PART 192                       // NDIR*NBLK = 256 partials
#define OFF_REF  512                       // B * 3N   (ref cloud, SoA)
#define OFF_TGT  (OFF_REF + Bb*3*Nn)       // NI * 3N  (target clouds)
#define OFF_PT2R (OFF_TGT + NI*3*Nn)       // NI * 3N  (target projected to ref)
#define OFF_PR2T (OFF_PT2R + NI*3*Nn)      // NI * 3N  (ref projected to target)

__device__ inline void rigid_inv(const float* P, float* Q) {
    // P row-major 4x4 rigid [R t; 0 1] -> [R^T, -R^T t; 0 1]
    Q[0] = P[0]; Q[1] = P[4]; Q[2]  = P[8];
    Q[4] = P[1]; Q[5] = P[5]; Q[6]  = P[9];
    Q[8] = P[2]; Q[9] = P[6]; Q[10] = P[10];
    Q[3]  = -(P[0]*P[3] + P[4]*P[7] + P[8]*P[11]);
    Q[7]  = -(P[1]*P[3] + P[5]*P[7] + P[9]*P[11]);
    Q[11] = -(P[2]*P[3] + P[6]*P[7] + P[10]*P[11]);
    Q[12] = 0.f; Q[13] = 0.f; Q[14] = 0.f; Q[15] = 1.f;
}

__device__ inline void mat44_mul(const float* A, const float* Bm, float* C) {
    for (int r = 0; r < 4; ++r)
        for (int c = 0; c < 4; ++c)
            C[r*4+c] = A[r*4+0]*Bm[0*4+c] + A[r*4+1]*Bm[1*4+c]
                     + A[r*4+2]*Bm[2*4+c] + A[r*4+3]*Bm[3*4+c];
}

__global__ void setup_kernel(const float* __restrict__ poses,
                             const float* __restrict__ masks,
                             const float* __restrict__ intr,
                             float* __restrict__ ws) {
    int tid = threadIdx.x;
    if (tid == 0) {
        // K inverse (cofactor), per batch
        for (int b = 0; b < Bb; ++b) {
            const float* Km = intr + b*9;
            float a = Km[0], b1 = Km[1], c = Km[2];
            float d = Km[3], e  = Km[4], f = Km[5];
            float g = Km[6], h  = Km[7], i9 = Km[8];
            float c00 =  (e*i9 - f*h);
            float c01 = -(b1*i9 - c*h);
            float c02 =  (b1*f - c*e);
            float c10 = -(d*i9 - f*g);
            float c11 =  (a*i9 - c*g);
            float c12 = -(a*f - c*d);
            float c20 =  (d*h - e*g);
            float c21 = -(a*h - b1*g);
            float c22 =  (a*e - b1*d);
            float det = a*c00 + b1*c10 + c*c20;
            float inv = 1.0f / det;
            float* Ki = ws + OFF_KINV + b*9;
            Ki[0] = c00*inv; Ki[1] = c01*inv; Ki[2] = c02*inv;
            Ki[3] = c10*inv; Ki[4] = c11*inv; Ki[5] = c12*inv;
            Ki[6] = c20*inv; Ki[7] = c21*inv; Ki[8] = c22*inv;
        }
        // relative pose matrices
        for (int b = 0; b < Bb; ++b) {
            const float* P0 = poses + (b*Vv + 0)*16;
            float inv0[16];
            rigid_inv(P0, inv0);
            for (int i = 1; i < Vv; ++i) {
                const float* Pi = poses + (b*Vv + i)*16;
                float invi[16];
                rigid_inv(Pi, invi);
                float* T = ws + OFF_TM + (b*(Vv-1) + (i-1))*32;
                mat44_mul(inv0, Pi, T);        // T_t2r = inv(ref) @ pose_i
                mat44_mul(invi, P0, T + 16);   // T_r2t = inv(pose_i) @ ref
            }
        }
    }
    __syncthreads();
    // mask sums: na = max(sum(mask), 1)
    __shared__ float red[4];
    for (int bv = 0; bv < Bb*Vv; ++bv) {
        float s = 0.f;
        for (int n = tid; n < Nn; n += 256) s += masks[bv*Nn + n];
        for (int off = 32; off > 0; off >>= 1) s += __shfl_down(s, off, 64);
        int lane = tid & 63, wv = tid >> 6;
        if (lane == 0) red[wv] = s;
        __syncthreads();
        if (tid == 0) ws[OFF_NA + bv] = fmaxf(red[0]+red[1]+red[2]+red[3], 1.0f);
        __syncthreads();
    }
}

__global__ void points_kernel(const float* __restrict__ depth,
                              float* __restrict__ ws) {
    int idx = blockIdx.x*blockDim.x + threadIdx.x;
    if (idx >= Bb*Nn) return;
    int b = idx / Nn, n = idx - b*Nn;
    float x = (float)(n & (Ww-1));
    float y = (float)(n >> 6);
    const float* Ki = ws + OFF_KINV + b*9;
    float cx = Ki[0]*x + Ki[1]*y + Ki[2];
    float cy = Ki[3]*x + Ki[4]*y + Ki[5];
    float cz = Ki[6]*x + Ki[7]*y + Ki[8];
    float dref = depth[(b*Vv + 0)*Nn + n];
    float rx = cx*dref, ry = cy*dref, rz = cz*dref;
    float* ref = ws + OFF_REF + b*3*Nn;
    ref[n] = rx; ref[Nn + n] = ry; ref[2*Nn + n] = rz;
    for (int i = 1; i < Vv; ++i) {
        int bi = b*(Vv-1) + (i-1);
        float di = depth[(b*Vv + i)*Nn + n];
        float tx = cx*di, ty = cy*di, tz = cz*di;
        float* tgt = ws + OFF_TGT + bi*3*Nn;
        tgt[n] = tx; tgt[Nn + n] = ty; tgt[2*Nn + n] = tz;
        const float* T = ws + OFF_TM + bi*32;     // T_t2r
        float* p2r = ws + OFF_PT2R + bi*3*Nn;
        p2r[n]        = T[0]*tx + T[1]*ty + T[2]*tz  + T[3];
        p2r[Nn + n]   = T[4]*tx + T[5]*ty + T[6]*tz  + T[7];
        p2r[2*Nn + n] = T[8]*tx + T[9]*ty + T[10]*tz + T[11];
        const float* U = T + 16;                   // T_r2t
        float* r2t = ws + OFF_PR2T + bi*3*Nn;
        r2t[n]        = U[0]*rx + U[1]*ry + U[2]*rz  + U[3];
        r2t[Nn + n]   = U[4]*rx + U[5]*ry + U[6]*rz  + U[7];
        r2t[2*Nn + n] = U[8]*rx + U[9]*ry + U[10]*rz + U[11];
    }
}

__global__ void __launch_bounds__(256) chamfer_kernel(const float* __restrict__ masks,
                                                      float* __restrict__ ws) {
    __shared__ float4 sB[TILE];
    __shared__ float red[4];
    int dir = blockIdx.x >> 4;    // which of 16 direction computations
    int blk = blockIdx.x & 15;    // which row-block
    int k   = dir & 3;            // 0: fwd a-rows, 1: fwd b-rows, 2: bwd a-rows, 3: bwd b-rows
    int bi  = dir >> 2;           // (b, i-1) combo
    int b   = bi / (Vv-1);
    int im1 = bi - b*(Vv-1);

    const float* ref = ws + OFF_REF  + b*3*Nn;
    const float* tgt = ws + OFF_TGT  + bi*3*Nn;
    const float* p2r = ws + OFF_PT2R + bi*3*Nn;
    const float* r2t = ws + OFF_PR2T + bi*3*Nn;
    const float* mref = masks + (b*Vv + 0)*Nn;
    const float* mtgt = masks + (b*Vv + im1 + 1)*Nn;
    float na_ref = ws[OFF_NA + b*Vv + 0];
    float na_tgt = ws[OFF_NA + b*Vv + im1 + 1];

    const float *A, *Bp, *wr, *mc;
    float norm;
    switch (k) {
        case 0:  A = ref; Bp = p2r; wr = mref; mc = mtgt; norm = na_ref; break;
        case 1:  A = p2r; Bp = ref; wr = mtgt; mc = mref; norm = na_tgt; break;
        case 2:  A = tgt; Bp = r2t; wr = mtgt; mc = mref; norm = na_tgt; break;
        default: A = r2t; Bp = tgt; wr = mref; mc = mtgt; norm = na_ref; break;
    }

    int tid = threadIdx.x;
    int r = blk*256 + tid;
    float ax = A[r], ay = A[Nn + r], az = A[2*Nn + r];
    float m0 = 3.0e38f, m1 = 3.0e38f, m2 = 3.0e38f, m3 = 3.0e38f;

    for (int t0 = 0; t0 < Nn; t0 += TILE) {
        __syncthreads();
        for (int j = tid; j < TILE; j += 256) {
            sB[j] = make_float4(Bp[t0 + j], Bp[Nn + t0 + j], Bp[2*Nn + t0 + j],
                                (1.0f - mc[t0 + j]) * BIGF);
        }
        __syncthreads();
        for (int j = 0; j < TILE; j += 4) {
            float4 p0 = sB[j], p1 = sB[j+1], p2 = sB[j+2], p3 = sB[j+3];
            float dx, dy, dz, d2;
            dx = ax - p0.x; dy = ay - p0.y; dz = az - p0.z;
            d2 = dx*dx + dy*dy + dz*dz + p0.w; m0 = fminf(m0, d2);
            dx = ax - p1.x; dy = ay - p1.y; dz = az - p1.z;
            d2 = dx*dx + dy*dy + dz*dz + p1.w; m1 = fminf(m1, d2);
            dx = ax - p2.x; dy = ay - p2.y; dz = az - p2.z;
            d2 = dx*dx + dy*dy + dz*dz + p2.w; m2 = fminf(m2, d2);
            dx = ax - p3.x; dy = ay - p3.y; dz = az - p3.z;
            d2 = dx*dx + dy*dy + dz*dz + p3.w; m3 = fminf(m3, d2);
        }
    }
    float dmin = fminf(fminf(m0, m1), fminf(m2, m3));
    float val = dmin * wr[r];
    for (int off = 32; off > 0; off >>= 1) val += __shfl_down(val, off, 64);
    int lane = tid & 63, wv = tid >> 6;
    if (lane == 0) red[wv] = val;
    __syncthreads();
    if (tid == 0) {
        float s = red[0] + red[1] + red[2] + red[3];
        ws[OFF_PART + blockIdx.x] = s / (norm * (float)(4*Bb*(Vv-1)));
    }
}

__global__ void final_kernel(const float* __restrict__ ws, float* __restrict__ out) {
    __shared__ float red[4];
    int tid = threadIdx.x;  // 256 == NDIR*NBLK
    float v = ws[OFF_PART + tid];
    for (int off = 32; off > 0; off >>= 1) v += __shfl_down(v, off, 64);
    if ((tid & 63) == 0) red[tid >> 6] = v;
    __syncthreads();
    if (tid == 0) out[0] = red[0] + red[1] + red[2] + red[3];
}

extern "C" void kernel_launch(void* const* d_in, const int* in_sizes, int n_in,
                              void* d_out, int out_size, void* d_ws, size_t ws_size,
                              hipStream_t stream) {
    // inputs: 0 views (unused), 1 poses, 2 masks, 3 intrinsics, 4 depth_maps, 5 num_views
    const float* poses = (const float*)d_in[1];
    const float* masks = (const float*)d_in[2];
    const float* intr  = (const float*)d_in[3];
    const float* depth = (const float*)d_in[4];
    float* ws  = (float*)d_ws;
    float* out = (float*)d_out;

    setup_kernel<<<1, 256, 0, stream>>>(poses, masks, intr, ws);
    points_kernel<<<(Bb*Nn + 255)/256, 256, 0, stream>>>(depth, ws);
    chamfer_kernel<<<NDIR*NBLK, 256, 0, stream>>>(masks, ws);
    final_kernel<<<1, 256, 0, stream>>>(ws, out);
}

// Round 2
// 75.636 us; speedup vs baseline: 1.5418x; 1.5418x over previous
//
#include <hip/hip_runtime.h>
#include <math.h>

// Problem shape (fixed by setup_inputs)
#define Bb 2
#define Vv 3
#define NI 4             // (b, view-pair) combos
#define Ww 64
#define Nn 4096          // points per cloud
#define NDIR 16          // 4 combos x 4 direction-cases
#define RPT 4            // rows per thread
#define TPB 256
#define ROWBLKS 4        // 4096 rows / (RPT*TPB)
#define NCHUNK 16        // column chunks
#define CCOLS 256        // Nn / NCHUNK
#define BIGF 1000000000.0f

// ws layout (float offsets)
#define OFF_ROWMIN 0               // NDIR*Nn uint keys = 65536
#define OFF_PK (NDIR*Nn)           // 14 clouds * Nn * 4 floats (packed x,y,z,|p|^2+maskBIG)
// cloud slots: ref[b] -> b ; tgt[bi] -> 2+bi ; p2r[bi] -> 6+bi ; r2t[bi] -> 10+bi

// order-preserving float->uint key (monotone for all finite floats)
__device__ __forceinline__ unsigned f2key(float f) {
    unsigned u = __float_as_uint(f);
    return (u & 0x80000000u) ? ~u : (u | 0x80000000u);
}
__device__ __forceinline__ float key2f(unsigned k) {
    return __uint_as_float((k & 0x80000000u) ? (k & 0x7fffffffu) : ~k);
}

__device__ __forceinline__ void rigid_inv(const float* __restrict__ P, float* Q) {
    Q[0] = P[0]; Q[1] = P[4]; Q[2]  = P[8];
    Q[4] = P[1]; Q[5] = P[5]; Q[6]  = P[9];
    Q[8] = P[2]; Q[9] = P[6]; Q[10] = P[10];
    Q[3]  = -(P[0]*P[3] + P[4]*P[7] + P[8]*P[11]);
    Q[7]  = -(P[1]*P[3] + P[5]*P[7] + P[9]*P[11]);
    Q[11] = -(P[2]*P[3] + P[6]*P[7] + P[10]*P[11]);
    Q[12] = 0.f; Q[13] = 0.f; Q[14] = 0.f; Q[15] = 1.f;
}

__device__ __forceinline__ void mat44_mul(const float* A, const float* Bm, float* C) {
    #pragma unroll
    for (int r = 0; r < 4; ++r)
        #pragma unroll
        for (int c = 0; c < 4; ++c)
            C[r*4+c] = A[r*4+0]*Bm[0*4+c] + A[r*4+1]*Bm[1*4+c]
                     + A[r*4+2]*Bm[2*4+c] + A[r*4+3]*Bm[3*4+c];
}

// Builds the 14 packed clouds (x,y,z, |p|^2 + (1-mask)*BIG) and inits rowmin keys.
__global__ void points_kernel(const float* __restrict__ poses,
                              const float* __restrict__ masks,
                              const float* __restrict__ intr,
                              const float* __restrict__ depth,
                              float* __restrict__ ws) {
    int idx = blockIdx.x*blockDim.x + threadIdx.x;   // 0..8191 (Bb*Nn)
    // init rowmin keys (65536 = 8 per thread)
    unsigned* rm = (unsigned*)ws;
    #pragma unroll
    for (int k = 0; k < 8; ++k) rm[idx + k*(Bb*Nn)] = 0xFFFFFFFFu;

    int b = idx >> 12, n = idx & (Nn-1);

    // K inverse (cofactor) — same for all threads of this b, cheap in registers
    const float* Km = intr + b*9;
    float ka = Km[0], kb = Km[1], kc = Km[2];
    float kd = Km[3], ke = Km[4], kf = Km[5];
    float kg = Km[6], kh = Km[7], ki = Km[8];
    float c00 =  (ke*ki - kf*kh);
    float c10 = -(kd*ki - kf*kg);
    float c20 =  (kd*kh - ke*kg);
    float det = ka*c00 + kb*c10 + kc*c20;
    float inv = 1.0f/det;
    float K00 = c00*inv,                K01 = -(kb*ki - kc*kh)*inv, K02 =  (kb*kf - kc*ke)*inv;
    float K10 = c10*inv,                K11 =  (ka*ki - kc*kg)*inv, K12 = -(ka*kf - kc*kd)*inv;
    float K20 = c20*inv,                K21 = -(ka*kh - kb*kg)*inv, K22 =  (ka*ke - kb*kd)*inv;

    float x = (float)(n & (Ww-1));
    float y = (float)(n >> 6);
    float cx = K00*x + K01*y + K02;
    float cy = K10*x + K11*y + K12;
    float cz = K20*x + K21*y + K22;

    float inv0[16];
    rigid_inv(poses + (b*Vv + 0)*16, inv0);

    float4* pk = (float4*)(ws + OFF_PK);

    float dref = depth[(b*Vv + 0)*Nn + n];
    float rx = cx*dref, ry = cy*dref, rz = cz*dref;
    float mref = masks[(b*Vv + 0)*Nn + n];
    float r2 = rx*rx + ry*ry + rz*rz;
    pk[b*Nn + n] = make_float4(rx, ry, rz, r2 + (1.0f - mref)*BIGF);

    #pragma unroll
    for (int i = 1; i < Vv; ++i) {
        int bi = b*(Vv-1) + (i-1);
        float invi[16], T[16], U[16];
        rigid_inv(poses + (b*Vv + i)*16, invi);
        mat44_mul(inv0, poses + (b*Vv + i)*16, T);   // T_t2r = inv(ref) @ pose_i
        mat44_mul(invi, poses + (b*Vv + 0)*16, U);   // T_r2t = inv(pose_i) @ ref

        float di = depth[(b*Vv + i)*Nn + n];
        float mi = masks[(b*Vv + i)*Nn + n];
        float tx = cx*di, ty = cy*di, tz = cz*di;
        float t2 = tx*tx + ty*ty + tz*tz;
        pk[(2 + bi)*Nn + n] = make_float4(tx, ty, tz, t2 + (1.0f - mi)*BIGF);

        float px = T[0]*tx + T[1]*ty + T[2]*tz  + T[3];
        float py = T[4]*tx + T[5]*ty + T[6]*tz  + T[7];
        float pz = T[8]*tx + T[9]*ty + T[10]*tz + T[11];
        float p2 = px*px + py*py + pz*pz;
        pk[(6 + bi)*Nn + n] = make_float4(px, py, pz, p2 + (1.0f - mi)*BIGF);

        float qx = U[0]*rx + U[1]*ry + U[2]*rz  + U[3];
        float qy = U[4]*rx + U[5]*ry + U[6]*rz  + U[7];
        float qz = U[8]*rx + U[9]*ry + U[10]*rz + U[11];
        float q2 = qx*qx + qy*qy + qz*qz;
        pk[(10 + bi)*Nn + n] = make_float4(qx, qy, qz, q2 + (1.0f - mref)*BIGF);
    }
}

__global__ void __launch_bounds__(TPB) chamfer_kernel(float* __restrict__ ws) {
    __shared__ float4 sB[CCOLS];
    int bid = blockIdx.x;
    int chunk  = bid & (NCHUNK-1);
    int rowblk = (bid >> 4) & (ROWBLKS-1);
    int dir    = bid >> 6;
    int k = dir & 3, bi = dir >> 2, b = bi >> 1;

    int slotA, slotB;
    switch (k) {
        case 0:  slotA = b;       slotB = 6 + bi;  break;  // fwd d_ab
        case 1:  slotA = 6 + bi;  slotB = b;       break;  // fwd d_ba
        case 2:  slotA = 2 + bi;  slotB = 10 + bi; break;  // bwd d_ab
        default: slotA = 10 + bi; slotB = 2 + bi;  break;  // bwd d_ba
    }
    const float4* pk = (const float4*)(ws + OFF_PK);
    int tid = threadIdx.x;

    sB[tid] = pk[slotB*Nn + chunk*CCOLS + tid];

    int r0 = rowblk*(RPT*TPB) + tid;
    float4 a[RPT];
    #pragma unroll
    for (int r = 0; r < RPT; ++r) a[r] = pk[slotA*Nn + r0 + r*TPB];
    __syncthreads();

    float acc0[RPT], acc1[RPT];
    #pragma unroll
    for (int r = 0; r < RPT; ++r) { acc0[r] = 3.0e38f; acc1[r] = 3.0e38f; }

    for (int j = 0; j < CCOLS; j += 4) {
        float4 c0 = sB[j], c1 = sB[j+1], c2 = sB[j+2], c3 = sB[j+3];
        #pragma unroll
        for (int r = 0; r < RPT; ++r) {
            float d0 = a[r].x*c0.x + a[r].y*c0.y + a[r].z*c0.z;
            float d1 = a[r].x*c1.x + a[r].y*c1.y + a[r].z*c1.z;
            float d2 = a[r].x*c2.x + a[r].y*c2.y + a[r].z*c2.z;
            float d3 = a[r].x*c3.x + a[r].y*c3.y + a[r].z*c3.z;
            float X0 = c0.w - 2.0f*d0;
            float X1 = c1.w - 2.0f*d1;
            float X2 = c2.w - 2.0f*d2;
            float X3 = c3.w - 2.0f*d3;
            acc0[r] = fminf(acc0[r], X0);
            acc1[r] = fminf(acc1[r], X1);
            acc0[r] = fminf(acc0[r], X2);
            acc1[r] = fminf(acc1[r], X3);
        }
    }

    unsigned* rm = (unsigned*)ws;
    #pragma unroll
    for (int r = 0; r < RPT; ++r) {
        float dmin = a[r].w + fminf(acc0[r], acc1[r]);   // add |a|^2 back
        atomicMin(&rm[dir*Nn + r0 + r*TPB], f2key(dmin));
    }
}

__global__ void __launch_bounds__(1024) final_kernel(const float* __restrict__ masks,
                                                     const float* __restrict__ ws,
                                                     float* __restrict__ out) {
    __shared__ float wred[16];
    __shared__ float s_inv_na[Bb*Vv];
    int tid = threadIdx.x;

    // na = max(sum(mask),1); store 1/(na*16)
    for (int bv = 0; bv < Bb*Vv; ++bv) {
        float s = 0.f;
        for (int n = tid; n < Nn; n += 1024) s += masks[bv*Nn + n];
        for (int off = 32; off > 0; off >>= 1) s += __shfl_down(s, off, 64);
        if ((tid & 63) == 0) wred[tid >> 6] = s;
        __syncthreads();
        if (tid == 0) {
            float t = 0.f;
            #pragma unroll
            for (int w = 0; w < 16; ++w) t += wred[w];
            s_inv_na[bv] = 1.0f / (fmaxf(t, 1.0f) * 16.0f);
        }
        __syncthreads();
    }

    const unsigned* rm = (const unsigned*)ws;
    float val = 0.f;
    for (int e = tid; e < NDIR*Nn; e += 1024) {
        int dir = e >> 12, r = e & (Nn-1);
        int k = dir & 3, bi = dir >> 2, b = bi >> 1, im1 = bi & 1;
        // row-weight mask & norm come from the same (b,view) slot
        int rowbv = (k == 0 || k == 3) ? (b*Vv) : (b*Vv + im1 + 1);
        float m = masks[rowbv*Nn + r];
        float d2 = key2f(rm[e]);
        val += d2 * m * s_inv_na[rowbv];
    }
    for (int off = 32; off > 0; off >>= 1) val += __shfl_down(val, off, 64);
    if ((tid & 63) == 0) wred[tid >> 6] = val;
    __syncthreads();
    if (tid == 0) {
        float t = 0.f;
        #pragma unroll
        for (int w = 0; w < 16; ++w) t += wred[w];
        out[0] = t;
    }
}

extern "C" void kernel_launch(void* const* d_in, const int* in_sizes, int n_in,
                              void* d_out, int out_size, void* d_ws, size_t ws_size,
                              hipStream_t stream) {
    // inputs: 0 views (unused), 1 poses, 2 masks, 3 intrinsics, 4 depth_maps, 5 num_views
    const float* poses = (const float*)d_in[1];
    const float* masks = (const float*)d_in[2];
    const float* intr  = (const float*)d_in[3];
    const float* depth = (const float*)d_in[4];
    float* ws  = (float*)d_ws;
    float* out = (float*)d_out;

    points_kernel<<<(Bb*Nn)/TPB, TPB, 0, stream>>>(poses, masks, intr, depth, ws);
    chamfer_kernel<<<NDIR*ROWBLKS*NCHUNK, TPB, 0, stream>>>(ws);
    final_kernel<<<1, 1024, 0, stream>>>(masks, ws, out);
}

// Round 3
// 69.577 us; speedup vs baseline: 1.6761x; 1.0871x over previous
//
#include <hip/hip_runtime.h>
#include <math.h>

// Problem shape (fixed by setup_inputs)
#define Bb 2
#define Vv 3
#define Nn 4096
#define NDIR 16
#define PADW 1.5e38f

// ws layout
#define OFF_CNT  65536   // int index: 16 counts (only 14 used)
#define OFF_PART 65552   // float index: 16 partials
#define OFF_CTR  65568   // uint index: finisher counter
#define OFF_PK   65576   // float index, 16B aligned: 14 clouds * 4096 * float4
// rm keys occupy ws[0..65535] as uints (16 dirs * 4096 rows)
// cloud slots: ref[b] -> b ; tgt[bi] -> 2+bi ; p2r[bi] -> 6+bi ; r2t[bi] -> 10+bi

__device__ __forceinline__ unsigned f2key(float f){
    unsigned u = __float_as_uint(f);
    return (u & 0x80000000u) ? ~u : (u | 0x80000000u);
}
__device__ __forceinline__ float key2f(unsigned k){
    return __uint_as_float((k & 0x80000000u) ? (k & 0x7fffffffu) : ~k);
}
__device__ __forceinline__ void slots_for_dir(int dir, int* sA, int* sB){
    int k = dir & 3, bi = dir >> 2, b = bi >> 1;
    switch (k){
        case 0:  *sA = b;       *sB = 6 + bi;  break;  // fwd d_ab: rows ref, cols p2r
        case 1:  *sA = 6 + bi;  *sB = b;       break;  // fwd d_ba
        case 2:  *sA = 2 + bi;  *sB = 10 + bi; break;  // bwd d_ab: rows tgt, cols r2t
        default: *sA = 10 + bi; *sB = 2 + bi;  break;  // bwd d_ba
    }
}

// One block per cloud slot (14) + 2 helper blocks. Builds packed (x,y,z,0.5*|p|^2)
// compacted to valid-mask points; writes counts; inits rowmin keys + counter.
__global__ void __launch_bounds__(1024) build_kernel(const float* __restrict__ poses,
                                                     const float* __restrict__ masks,
                                                     const float* __restrict__ intr,
                                                     const float* __restrict__ depth,
                                                     float* __restrict__ ws){
    int blk = blockIdx.x, tid = threadIdx.x;
    unsigned* rm = (unsigned*)ws;
    #pragma unroll
    for (int k2 = 0; k2 < 4; ++k2) rm[blk*4096 + k2*1024 + tid] = 0xFFFFFFFFu;
    if (blk == 15 && tid == 0) ((unsigned*)ws)[OFF_CTR] = 0u;
    if (blk >= 14) return;

    int slot = blk, type, b, im1;
    if (slot < 2)      { type = 0; b = slot;         im1 = 0; }
    else if (slot < 6) { type = 1; b = (slot-2)>>1;  im1 = (slot-2)&1; }
    else if (slot < 10){ type = 2; b = (slot-6)>>1;  im1 = (slot-6)&1; }
    else               { type = 3; b = (slot-10)>>1; im1 = (slot-10)&1; }
    int vi = im1 + 1;
    int mview = (type==0 || type==3) ? 0 : vi;   // mask ownership
    int dview = (type==0 || type==3) ? 0 : vi;   // depth source

    // K inverse (cofactor)
    const float* Km = intr + b*9;
    float ka=Km[0],kb=Km[1],kc=Km[2],kd=Km[3],ke=Km[4],kf=Km[5],kg=Km[6],kh=Km[7],ki=Km[8];
    float c00=(ke*ki-kf*kh), c10=-(kd*ki-kf*kg), c20=(kd*kh-ke*kg);
    float det = ka*c00 + kb*c10 + kc*c20, iv = 1.0f/det;
    float Ki[9] = { c00*iv, -(kb*ki-kc*kh)*iv,  (kb*kf-kc*ke)*iv,
                    c10*iv,  (ka*ki-kc*kg)*iv, -(ka*kf-kc*kd)*iv,
                    c20*iv, -(ka*kh-kb*kg)*iv,  (ka*ke-kb*kd)*iv };
    float M[9], tv[3] = {0.f, 0.f, 0.f};
    if (type < 2){
        #pragma unroll
        for (int i = 0; i < 9; ++i) M[i] = Ki[i];
    } else {
        const float* P0 = poses + (b*Vv + 0)*16;
        const float* Pi = poses + (b*Vv + vi)*16;
        float R[9];
        if (type == 2){  // T_t2r = inv(pose0) @ pose_i : R = R0^T Ri, t = R0^T (ti - t0)
            #pragma unroll
            for (int r = 0; r < 3; ++r){
                #pragma unroll
                for (int c = 0; c < 3; ++c)
                    R[r*3+c] = P0[0*4+r]*Pi[0*4+c] + P0[1*4+r]*Pi[1*4+c] + P0[2*4+r]*Pi[2*4+c];
                tv[r] = P0[0*4+r]*(Pi[3]-P0[3]) + P0[1*4+r]*(Pi[7]-P0[7]) + P0[2*4+r]*(Pi[11]-P0[11]);
            }
        } else {         // T_r2t = inv(pose_i) @ pose0 : R = Ri^T R0, t = Ri^T (t0 - ti)
            #pragma unroll
            for (int r = 0; r < 3; ++r){
                #pragma unroll
                for (int c = 0; c < 3; ++c)
                    R[r*3+c] = Pi[0*4+r]*P0[0*4+c] + Pi[1*4+r]*P0[1*4+c] + Pi[2*4+r]*P0[2*4+c];
                tv[r] = Pi[0*4+r]*(P0[3]-Pi[3]) + Pi[1*4+r]*(P0[7]-Pi[7]) + Pi[2*4+r]*(P0[11]-Pi[11]);
            }
        }
        #pragma unroll
        for (int r = 0; r < 3; ++r)
            #pragma unroll
            for (int c = 0; c < 3; ++c)
                M[r*3+c] = R[r*3+0]*Ki[0*3+c] + R[r*3+1]*Ki[1*3+c] + R[r*3+2]*Ki[2*3+c];
    }

    int n0 = tid*4;
    const float4 dd = *(const float4*)(depth + (b*Vv + dview)*Nn + n0);
    const float4 mm = *(const float4*)(masks + (b*Vv + mview)*Nn + n0);
    float dar[4] = {dd.x, dd.y, dd.z, dd.w};
    float mar[4] = {mm.x, mm.y, mm.z, mm.w};
    float4 pt[4]; int fl[4];
    #pragma unroll
    for (int k2 = 0; k2 < 4; ++k2){
        int n = n0 + k2;
        float x = (float)(n & 63), y = (float)(n >> 6);
        float ux = M[0]*x + M[1]*y + M[2];
        float uy = M[3]*x + M[4]*y + M[5];
        float uz = M[6]*x + M[7]*y + M[8];
        float d = dar[k2];
        float px = ux*d + tv[0], py = uy*d + tv[1], pz = uz*d + tv[2];
        pt[k2] = make_float4(px, py, pz, 0.5f*(px*px + py*py + pz*pz));
        fl[k2] = mar[k2] > 0.5f ? 1 : 0;
    }
    int ts = fl[0] + fl[1] + fl[2] + fl[3];
    int lane = tid & 63, wid = tid >> 6;
    int inc = ts;
    #pragma unroll
    for (int off = 1; off < 64; off <<= 1){
        int v = __shfl_up(inc, off);
        if (lane >= off) inc += v;
    }
    __shared__ int wsum[16], woff[16];
    if (lane == 63) wsum[wid] = inc;
    __syncthreads();
    if (tid == 0){
        int acc = 0;
        #pragma unroll
        for (int w = 0; w < 16; ++w){ woff[w] = acc; acc += wsum[w]; }
        ((int*)ws)[OFF_CNT + slot] = acc;
    }
    __syncthreads();
    int pos = woff[wid] + inc - ts;   // exclusive prefix
    float4* out = (float4*)(ws + OFF_PK) + slot*Nn;
    #pragma unroll
    for (int k2 = 0; k2 < 4; ++k2){ if (fl[k2]) out[pos++] = pt[k2]; }
}

// grid: 16 dirs x 8 rowblks(512 rows) x 16 chunks(256 cols); early-exit past counts.
__global__ void __launch_bounds__(256) chamfer_kernel(float* __restrict__ ws){
    int bid = blockIdx.x;
    int chunk  = bid & 15;
    int rowblk = (bid >> 4) & 7;
    int dir    = bid >> 7;
    int slotA, slotB;
    slots_for_dir(dir, &slotA, &slotB);
    const int* cnt = (const int*)ws + OFF_CNT;
    int cntA = cnt[slotA], cntB = cnt[slotB];
    if (rowblk*512 >= cntA || chunk*256 >= cntB) return;

    __shared__ float4 sB[256];
    const float4* pk = (const float4*)(ws + OFF_PK);
    int tid = threadIdx.x;
    int col = chunk*256 + tid;
    sB[tid] = (col < cntB) ? pk[slotB*Nn + col] : make_float4(0.f, 0.f, 0.f, PADW);

    int r0 = rowblk*512 + tid;
    int r1 = r0 + 256;
    r0 = min(r0, cntA-1);
    r1 = min(r1, cntA-1);
    float4 a0 = pk[slotA*Nn + r0];
    float4 a1 = pk[slotA*Nn + r1];
    __syncthreads();

    float m00 = -3.0e38f, m01 = -3.0e38f, m10 = -3.0e38f, m11 = -3.0e38f;
    for (int j = 0; j < 256; j += 4){
        float4 c0 = sB[j], c1 = sB[j+1], c2 = sB[j+2], c3 = sB[j+3];
        float t00 = fmaf(a0.z, c0.z, fmaf(a0.y, c0.y, fmaf(a0.x, c0.x, -c0.w)));
        float t01 = fmaf(a0.z, c1.z, fmaf(a0.y, c1.y, fmaf(a0.x, c1.x, -c1.w)));
        float t02 = fmaf(a0.z, c2.z, fmaf(a0.y, c2.y, fmaf(a0.x, c2.x, -c2.w)));
        float t03 = fmaf(a0.z, c3.z, fmaf(a0.y, c3.y, fmaf(a0.x, c3.x, -c3.w)));
        float t10 = fmaf(a1.z, c0.z, fmaf(a1.y, c0.y, fmaf(a1.x, c0.x, -c0.w)));
        float t11 = fmaf(a1.z, c1.z, fmaf(a1.y, c1.y, fmaf(a1.x, c1.x, -c1.w)));
        float t12 = fmaf(a1.z, c2.z, fmaf(a1.y, c2.y, fmaf(a1.x, c2.x, -c2.w)));
        float t13 = fmaf(a1.z, c3.z, fmaf(a1.y, c3.y, fmaf(a1.x, c3.x, -c3.w)));
        m00 = fmaxf(fmaxf(t00, t01), m00);   // v_max3
        m01 = fmaxf(fmaxf(t02, t03), m01);
        m10 = fmaxf(fmaxf(t10, t11), m10);
        m11 = fmaxf(fmaxf(t12, t13), m11);
    }
    unsigned* rm = (unsigned*)ws;
    float dmin0 = 2.0f*(a0.w - fmaxf(m00, m01));   // = |a|^2 - 2*max(dot - |b|^2/2)
    float dmin1 = 2.0f*(a1.w - fmaxf(m10, m11));
    atomicMin(&rm[dir*Nn + r0], f2key(dmin0));
    atomicMin(&rm[dir*Nn + r1], f2key(dmin1));
}

// 16 blocks, one per dir; last-done block does the deterministic 16-way sum.
__global__ void __launch_bounds__(256) final_kernel(float* __restrict__ ws,
                                                    float* __restrict__ out){
    int dir = blockIdx.x, tid = threadIdx.x;
    int slotA, slotB;
    slots_for_dir(dir, &slotA, &slotB);
    int cntA = ((const int*)ws)[OFF_CNT + slotA];
    const unsigned* rm = (const unsigned*)ws;
    float s = 0.f;
    for (int r = tid; r < cntA; r += 256) s += key2f(rm[dir*Nn + r]);
    for (int off = 32; off > 0; off >>= 1) s += __shfl_down(s, off, 64);
    __shared__ float red[4];
    if ((tid & 63) == 0) red[tid >> 6] = s;
    __syncthreads();
    if (tid == 0){
        float tot = red[0] + red[1] + red[2] + red[3];
        float na = fmaxf((float)cntA, 1.0f);
        atomicExch(ws + OFF_PART + dir, tot / (na * 16.0f));
        __threadfence();
        unsigned old = atomicAdd((unsigned*)ws + OFF_CTR, 1u);
        if (old == NDIR - 1){
            float tt = 0.f;
            #pragma unroll
            for (int i = 0; i < NDIR; ++i) tt += atomicAdd(ws + OFF_PART + i, 0.0f);
            out[0] = tt;
        }
    }
}

extern "C" void kernel_launch(void* const* d_in, const int* in_sizes, int n_in,
                              void* d_out, int out_size, void* d_ws, size_t ws_size,
                              hipStream_t stream) {
    // inputs: 0 views (unused), 1 poses, 2 masks, 3 intrinsics, 4 depth_maps, 5 num_views
    const float* poses = (const float*)d_in[1];
    const float* masks = (const float*)d_in[2];
    const float* intr  = (const float*)d_in[3];
    const float* depth = (const float*)d_in[4];
    float* ws  = (float*)d_ws;
    float* out = (float*)d_out;

    build_kernel<<<16, 1024, 0, stream>>>(poses, masks, intr, depth, ws);
    chamfer_kernel<<<NDIR*8*16, 256, 0, stream>>>(ws);
    final_kernel<<<NDIR, 256, 0, stream>>>(ws, out);
}

// Round 4
// 35.806 us; speedup vs baseline: 3.2569x; 1.9432x over previous
//
#include <hip/hip_runtime.h>
#include <math.h>

// Problem shape (fixed by setup_inputs)
#define Bb 2
#define Vv 3
#define Nn 4096
#define NDIR 16
#define RPB 64           // rows per block
#define NRB 64           // row-blocks per dir (covers up to 4096 rows)
#define TCOLS 512        // column tile in LDS
#define PADW 1.5e38f

// ws layout (float indices)
#define OFF_PART 0       // 1024 block partials
#define OFF_CTR  1024    // finisher counter (uint)
#define OFF_CNT  1040    // 16 ints (14 used): compacted counts
#define OFF_PK   1056    // 14 clouds * 4096 * float4 (x,y,z, 0.5*|p|^2)
// cloud slots: ref[b] -> b ; tgt[bi] -> 2+bi ; p2r[bi] -> 6+bi ; r2t[bi] -> 10+bi

__device__ __forceinline__ void slots_for_dir(int dir, int* sA, int* sB){
    int k = dir & 3, bi = dir >> 2, b = bi >> 1;
    switch (k){
        case 0:  *sA = b;       *sB = 6 + bi;  break;  // fwd d_ab: rows ref, cols p2r
        case 1:  *sA = 6 + bi;  *sB = b;       break;  // fwd d_ba
        case 2:  *sA = 2 + bi;  *sB = 10 + bi; break;  // bwd d_ab: rows tgt, cols r2t
        default: *sA = 10 + bi; *sB = 2 + bi;  break;  // bwd d_ba
    }
}

// 14 blocks, one per cloud slot. Builds packed (x,y,z,0.5*|p|^2) compacted to
// valid-mask points; writes counts; block 0 resets the finisher counter.
__global__ void __launch_bounds__(1024) build_kernel(const float* __restrict__ poses,
                                                     const float* __restrict__ masks,
                                                     const float* __restrict__ intr,
                                                     const float* __restrict__ depth,
                                                     float* __restrict__ ws){
    int slot = blockIdx.x, tid = threadIdx.x;
    if (slot == 0 && tid == 0) ((unsigned*)ws)[OFF_CTR] = 0u;

    int type, b, im1;
    if (slot < 2)      { type = 0; b = slot;         im1 = 0; }
    else if (slot < 6) { type = 1; b = (slot-2)>>1;  im1 = (slot-2)&1; }
    else if (slot < 10){ type = 2; b = (slot-6)>>1;  im1 = (slot-6)&1; }
    else               { type = 3; b = (slot-10)>>1; im1 = (slot-10)&1; }
    int vi = im1 + 1;
    int mview = (type==0 || type==3) ? 0 : vi;   // mask ownership
    int dview = (type==0 || type==3) ? 0 : vi;   // depth source

    // K inverse (cofactor)
    const float* Km = intr + b*9;
    float ka=Km[0],kb=Km[1],kc=Km[2],kd=Km[3],ke=Km[4],kf=Km[5],kg=Km[6],kh=Km[7],ki=Km[8];
    float c00=(ke*ki-kf*kh), c10=-(kd*ki-kf*kg), c20=(kd*kh-ke*kg);
    float det = ka*c00 + kb*c10 + kc*c20, iv = 1.0f/det;
    float Ki[9] = { c00*iv, -(kb*ki-kc*kh)*iv,  (kb*kf-kc*ke)*iv,
                    c10*iv,  (ka*ki-kc*kg)*iv, -(ka*kf-kc*kd)*iv,
                    c20*iv, -(ka*kh-kb*kg)*iv,  (ka*ke-kb*kd)*iv };
    float M[9], tv[3] = {0.f, 0.f, 0.f};
    if (type < 2){
        #pragma unroll
        for (int i = 0; i < 9; ++i) M[i] = Ki[i];
    } else {
        const float* P0 = poses + (b*Vv + 0)*16;
        const float* Pi = poses + (b*Vv + vi)*16;
        float R[9];
        if (type == 2){  // inv(pose0) @ pose_i
            #pragma unroll
            for (int r = 0; r < 3; ++r){
                #pragma unroll
                for (int c = 0; c < 3; ++c)
                    R[r*3+c] = P0[0*4+r]*Pi[0*4+c] + P0[1*4+r]*Pi[1*4+c] + P0[2*4+r]*Pi[2*4+c];
                tv[r] = P0[0*4+r]*(Pi[3]-P0[3]) + P0[1*4+r]*(Pi[7]-P0[7]) + P0[2*4+r]*(Pi[11]-P0[11]);
            }
        } else {         // inv(pose_i) @ pose0
            #pragma unroll
            for (int r = 0; r < 3; ++r){
                #pragma unroll
                for (int c = 0; c < 3; ++c)
                    R[r*3+c] = Pi[0*4+r]*P0[0*4+c] + Pi[1*4+r]*P0[1*4+c] + Pi[2*4+r]*P0[2*4+c];
                tv[r] = Pi[0*4+r]*(P0[3]-Pi[3]) + Pi[1*4+r]*(P0[7]-Pi[7]) + Pi[2*4+r]*(P0[11]-Pi[11]);
            }
        }
        #pragma unroll
        for (int r = 0; r < 3; ++r)
            #pragma unroll
            for (int c = 0; c < 3; ++c)
                M[r*3+c] = R[r*3+0]*Ki[0*3+c] + R[r*3+1]*Ki[1*3+c] + R[r*3+2]*Ki[2*3+c];
    }

    int n0 = tid*4;
    const float4 dd = *(const float4*)(depth + (b*Vv + dview)*Nn + n0);
    const float4 mm = *(const float4*)(masks + (b*Vv + mview)*Nn + n0);
    float dar[4] = {dd.x, dd.y, dd.z, dd.w};
    float mar[4] = {mm.x, mm.y, mm.z, mm.w};
    float4 pt[4]; int fl[4];
    #pragma unroll
    for (int k2 = 0; k2 < 4; ++k2){
        int n = n0 + k2;
        float x = (float)(n & 63), y = (float)(n >> 6);
        float ux = M[0]*x + M[1]*y + M[2];
        float uy = M[3]*x + M[4]*y + M[5];
        float uz = M[6]*x + M[7]*y + M[8];
        float d = dar[k2];
        float px = ux*d + tv[0], py = uy*d + tv[1], pz = uz*d + tv[2];
        pt[k2] = make_float4(px, py, pz, 0.5f*(px*px + py*py + pz*pz));
        fl[k2] = mar[k2] > 0.5f ? 1 : 0;
    }
    int ts = fl[0] + fl[1] + fl[2] + fl[3];
    int lane = tid & 63, wid = tid >> 6;
    int inc = ts;
    #pragma unroll
    for (int off = 1; off < 64; off <<= 1){
        int v = __shfl_up(inc, off);
        if (lane >= off) inc += v;
    }
    __shared__ int wsum[16], woff[16];
    if (lane == 63) wsum[wid] = inc;
    __syncthreads();
    if (tid == 0){
        int acc = 0;
        #pragma unroll
        for (int w = 0; w < 16; ++w){ woff[w] = acc; acc += wsum[w]; }
        ((int*)ws)[OFF_CNT + slot] = acc;
    }
    __syncthreads();
    int pos = woff[wid] + inc - ts;   // exclusive prefix
    float4* outp = (float4*)(ws + OFF_PK) + slot*Nn;
    #pragma unroll
    for (int k2 = 0; k2 < 4; ++k2){ if (fl[k2]) outp[pos++] = pt[k2]; }
}

// grid: 16 dirs x 64 rowblocks (64 rows each). Each block computes complete
// row-mins over ALL columns (no cross-block atomics), emits one partial.
// Last-done block sums all 1024 partials (fixed order -> deterministic).
__global__ void __launch_bounds__(256) chamfer_kernel(float* __restrict__ ws,
                                                      float* __restrict__ out){
    __shared__ float4 sB[TCOLS];
    __shared__ float red[16];
    __shared__ float fred[4];
    __shared__ int lastFlag;

    int bid = blockIdx.x;
    int rowblk = bid & (NRB-1);
    int dir    = bid >> 6;
    int slotA, slotB;
    slots_for_dir(dir, &slotA, &slotB);
    const int* cnt = (const int*)ws + OFF_CNT;
    int cntA = cnt[slotA], cntB = cnt[slotB];

    int tid = threadIdx.x;
    int rowgrp = tid >> 4, colpart = tid & 15;

    float partial = 0.f;
    bool active = (rowblk*RPB < cntA) && (cntB > 0);
    if (active){
        const float4* pk = (const float4*)(ws + OFF_PK);
        int rbase = rowblk*RPB + rowgrp*4;
        float4 a[4];
        #pragma unroll
        for (int rr = 0; rr < 4; ++rr)
            a[rr] = pk[slotA*Nn + min(rbase + rr, cntA-1)];

        float m0 = -3.0e38f, m1 = -3.0e38f, m2 = -3.0e38f, m3 = -3.0e38f;
        for (int t0 = 0; t0 < cntB; t0 += TCOLS){
            __syncthreads();
            #pragma unroll
            for (int k = 0; k < 2; ++k){
                int idx = tid + k*256;
                int cg = t0 + idx;
                sB[idx] = (cg < cntB) ? pk[slotB*Nn + cg]
                                      : make_float4(0.f, 0.f, 0.f, PADW);
            }
            __syncthreads();
            const float4* sbp = sB + colpart;   // stride-16: 2-way banking (free)
            #pragma unroll
            for (int i = 0; i < 32; i += 2){
                float4 c0 = sbp[16*i];
                float4 c1 = sbp[16*(i+1)];
                float u00 = fmaf(a[0].z,c0.z, fmaf(a[0].y,c0.y, fmaf(a[0].x,c0.x, -c0.w)));
                float u01 = fmaf(a[0].z,c1.z, fmaf(a[0].y,c1.y, fmaf(a[0].x,c1.x, -c1.w)));
                float u10 = fmaf(a[1].z,c0.z, fmaf(a[1].y,c0.y, fmaf(a[1].x,c0.x, -c0.w)));
                float u11 = fmaf(a[1].z,c1.z, fmaf(a[1].y,c1.y, fmaf(a[1].x,c1.x, -c1.w)));
                float u20 = fmaf(a[2].z,c0.z, fmaf(a[2].y,c0.y, fmaf(a[2].x,c0.x, -c0.w)));
                float u21 = fmaf(a[2].z,c1.z, fmaf(a[2].y,c1.y, fmaf(a[2].x,c1.x, -c1.w)));
                float u30 = fmaf(a[3].z,c0.z, fmaf(a[3].y,c0.y, fmaf(a[3].x,c0.x, -c0.w)));
                float u31 = fmaf(a[3].z,c1.z, fmaf(a[3].y,c1.y, fmaf(a[3].x,c1.x, -c1.w)));
                m0 = fmaxf(fmaxf(u00, u01), m0);   // v_max3
                m1 = fmaxf(fmaxf(u10, u11), m1);
                m2 = fmaxf(fmaxf(u20, u21), m2);
                m3 = fmaxf(fmaxf(u30, u31), m3);
            }
        }
        // exact per-row max over the 16 colparts (within-wave butterfly)
        #pragma unroll
        for (int off = 1; off < 16; off <<= 1){
            m0 = fmaxf(m0, __shfl_xor(m0, off, 64));
            m1 = fmaxf(m1, __shfl_xor(m1, off, 64));
            m2 = fmaxf(m2, __shfl_xor(m2, off, 64));
            m3 = fmaxf(m3, __shfl_xor(m3, off, 64));
        }
        float s = 0.f;
        if (rbase + 0 < cntA) s += 2.0f*(a[0].w - m0);
        if (rbase + 1 < cntA) s += 2.0f*(a[1].w - m1);
        if (rbase + 2 < cntA) s += 2.0f*(a[2].w - m2);
        if (rbase + 3 < cntA) s += 2.0f*(a[3].w - m3);
        if (colpart == 0) red[rowgrp] = s;
        __syncthreads();
        if (tid == 0){
            float tsum = 0.f;
            #pragma unroll
            for (int g = 0; g < 16; ++g) tsum += red[g];
            float na = fmaxf((float)cntA, 1.0f);
            partial = tsum / (na * 16.0f);
        }
    }

    // publish partial + finisher election (proven R2 pattern)
    if (tid == 0){
        atomicExch(ws + OFF_PART + bid, partial);
        __threadfence();
        unsigned old = atomicAdd((unsigned*)ws + OFF_CTR, 1u);
        lastFlag = (old == (unsigned)(NDIR*NRB - 1)) ? 1 : 0;
    }
    __syncthreads();
    if (lastFlag){
        float v = 0.f;
        #pragma unroll
        for (int k = 0; k < 4; ++k)
            v += atomicAdd(ws + OFF_PART + tid*4 + k, 0.0f);   // coherent read
        for (int off = 32; off > 0; off >>= 1) v += __shfl_down(v, off, 64);
        if ((tid & 63) == 0) fred[tid >> 6] = v;
        __syncthreads();
        if (tid == 0) out[0] = fred[0] + fred[1] + fred[2] + fred[3];
    }
}

extern "C" void kernel_launch(void* const* d_in, const int* in_sizes, int n_in,
                              void* d_out, int out_size, void* d_ws, size_t ws_size,
                              hipStream_t stream) {
    // inputs: 0 views (unused), 1 poses, 2 masks, 3 intrinsics, 4 depth_maps, 5 num_views
    const float* poses = (const float*)d_in[1];
    const float* masks = (const float*)d_in[2];
    const float* intr  = (const float*)d_in[3];
    const float* depth = (const float*)d_in[4];
    float* ws  = (float*)d_ws;
    float* out = (float*)d_out;

    build_kernel<<<14, 1024, 0, stream>>>(poses, masks, intr, depth, ws);
    chamfer_kernel<<<NDIR*NRB, 256, 0, stream>>>(ws, out);
}

// Round 5
// 25.942 us; speedup vs baseline: 4.4953x; 1.3802x over previous
//
#include <hip/hip_runtime.h>
#include <math.h>

// Problem shape (fixed by setup_inputs)
#define Bb 2
#define Vv 3
#define Nn 4096
#define NDIR 16
#define NRB 32           // rowblocks per dir
#define RPB 128          // rows per block
#define NBLKS (NDIR*NRB) // 512
#define PADW 1.5e38f

// ws: [0..511] block partials (plain float)

__device__ __forceinline__ void slots_for_dir(int dir, int* sA, int* sB){
    int k = dir & 3, bi = dir >> 2, b = bi >> 1;
    switch (k){
        case 0:  *sA = b;       *sB = 6 + bi;  break;  // fwd d_ab: rows ref, cols p2r
        case 1:  *sA = 6 + bi;  *sB = b;       break;  // fwd d_ba
        case 2:  *sA = 2 + bi;  *sB = 10 + bi; break;  // bwd d_ab: rows tgt, cols r2t
        default: *sA = 10 + bi; *sB = 2 + bi;  break;  // bwd d_ba
    }
}

// slot -> (b, view for depth/mask, M[9], tv[3]) ; point = M*(x,y,1)*d + tv
__device__ __forceinline__ void build_matrix(int slot,
                                             const float* __restrict__ poses,
                                             const float* __restrict__ intr,
                                             float* M, float* tv, int* bOut, int* vOut){
    int type, b, im1;
    if (slot < 2)      { type = 0; b = slot;         im1 = 0; }
    else if (slot < 6) { type = 1; b = (slot-2)>>1;  im1 = (slot-2)&1; }
    else if (slot < 10){ type = 2; b = (slot-6)>>1;  im1 = (slot-6)&1; }
    else               { type = 3; b = (slot-10)>>1; im1 = (slot-10)&1; }
    int vi = im1 + 1;
    *bOut = b;
    *vOut = (type==0 || type==3) ? 0 : vi;   // depth & mask view

    const float* Km = intr + b*9;
    float ka=Km[0],kb=Km[1],kc=Km[2],kd=Km[3],ke=Km[4],kf=Km[5],kg=Km[6],kh=Km[7],ki=Km[8];
    float c00=(ke*ki-kf*kh), c10=-(kd*ki-kf*kg), c20=(kd*kh-ke*kg);
    float det = ka*c00 + kb*c10 + kc*c20, iv = 1.0f/det;
    float Ki[9] = { c00*iv, -(kb*ki-kc*kh)*iv,  (kb*kf-kc*ke)*iv,
                    c10*iv,  (ka*ki-kc*kg)*iv, -(ka*kf-kc*kd)*iv,
                    c20*iv, -(ka*kh-kb*kg)*iv,  (ka*ke-kb*kd)*iv };
    tv[0] = tv[1] = tv[2] = 0.f;
    if (type < 2){
        #pragma unroll
        for (int i = 0; i < 9; ++i) M[i] = Ki[i];
        return;
    }
    const float* P0 = poses + (b*Vv + 0)*16;
    const float* Pi = poses + (b*Vv + vi)*16;
    float R[9];
    if (type == 2){  // inv(pose0) @ pose_i
        #pragma unroll
        for (int r = 0; r < 3; ++r){
            #pragma unroll
            for (int c = 0; c < 3; ++c)
                R[r*3+c] = P0[0*4+r]*Pi[0*4+c] + P0[1*4+r]*Pi[1*4+c] + P0[2*4+r]*Pi[2*4+c];
            tv[r] = P0[0*4+r]*(Pi[3]-P0[3]) + P0[1*4+r]*(Pi[7]-P0[7]) + P0[2*4+r]*(Pi[11]-P0[11]);
        }
    } else {         // inv(pose_i) @ pose0
        #pragma unroll
        for (int r = 0; r < 3; ++r){
            #pragma unroll
            for (int c = 0; c < 3; ++c)
                R[r*3+c] = Pi[0*4+r]*P0[0*4+c] + Pi[1*4+r]*P0[1*4+c] + Pi[2*4+r]*P0[2*4+c];
            tv[r] = Pi[0*4+r]*(P0[3]-Pi[3]) + Pi[1*4+r]*(P0[7]-Pi[7]) + Pi[2*4+r]*(P0[11]-Pi[11]);
        }
    }
    #pragma unroll
    for (int r = 0; r < 3; ++r)
        #pragma unroll
        for (int c = 0; c < 3; ++c)
            M[r*3+c] = R[r*3+0]*Ki[0*3+c] + R[r*3+1]*Ki[1*3+c] + R[r*3+2]*Ki[2*3+c];
}

// Fully fused: each block builds (redundantly) its compacted A-row slice and the
// full compacted B cloud in LDS, computes exact row-mins over all columns, and
// writes one pre-normalized partial. No cross-block atomics at all.
__global__ void __launch_bounds__(256) fused_kernel(const float* __restrict__ poses,
                                                    const float* __restrict__ masks,
                                                    const float* __restrict__ intr,
                                                    const float* __restrict__ depth,
                                                    float* __restrict__ ws){
    __shared__ float4 sB[Nn + 16];   // 65792 B
    __shared__ float4 sA[RPB];       // 2048 B
    __shared__ int   wsum[4];
    __shared__ float sred[32];

    int bid = blockIdx.x;
    int rowblk = bid & (NRB-1);
    int dir    = bid >> 5;
    int slotA, slotB;
    slots_for_dir(dir, &slotA, &slotB);

    int tid = threadIdx.x;
    int lane = tid & 63, wv = tid >> 6;

    // ---- matrices for both clouds (redundant per thread, cheap) ----
    float MA[9], tA[3], MB[9], tB[3];
    int b, vA, vB, bdummy;
    build_matrix(slotA, poses, intr, MA, tA, &b, &vA);
    build_matrix(slotB, poses, intr, MB, tB, &bdummy, &vB);

    // ---- A phase: mask scan to find cntA and this block's row slice ----
    unsigned flA = 0; int tsA = 0;
    {
        const float* mb = masks + (b*Vv + vA)*Nn + tid*16;
        #pragma unroll
        for (int q = 0; q < 4; ++q){
            float4 m4 = *(const float4*)(mb + q*4);
            const float* mv = (const float*)&m4;
            #pragma unroll
            for (int r = 0; r < 4; ++r)
                if (mv[r] > 0.5f){ flA |= 1u << (q*4 + r); ++tsA; }
        }
    }
    int inc = tsA;
    #pragma unroll
    for (int off = 1; off < 64; off <<= 1){
        int t = __shfl_up(inc, off, 64);
        if (lane >= off) inc += t;
    }
    if (lane == 63) wsum[wv] = inc;
    __syncthreads();
    int base = inc - tsA;
    #pragma unroll
    for (int w = 0; w < 4; ++w) if (w < wv) base += wsum[w];
    int cntA = wsum[0] + wsum[1] + wsum[2] + wsum[3];

    int lo = rowblk * RPB;
    int nRows = min(cntA - lo, RPB);
    if (nRows <= 0){                 // uniform branch
        if (tid == 0) ws[bid] = 0.f;
        return;
    }

    // write A slice points
    {
        const float* dbase = depth + (b*Vv + vA)*Nn;
        int p = base;
        #pragma unroll
        for (int k = 0; k < 16; ++k){
            if (flA & (1u << k)){
                int rel = p - lo;
                if (rel >= 0 && rel < RPB){
                    int n = tid*16 + k;
                    float d = dbase[n];
                    float x = (float)(n & 63), y = (float)(n >> 6);
                    float ux = fmaf(MA[0],x, fmaf(MA[1],y, MA[2]));
                    float uy = fmaf(MA[3],x, fmaf(MA[4],y, MA[5]));
                    float uz = fmaf(MA[6],x, fmaf(MA[7],y, MA[8]));
                    float px = fmaf(ux,d,tA[0]), py = fmaf(uy,d,tA[1]), pz = fmaf(uz,d,tA[2]);
                    sA[rel] = make_float4(px,py,pz, 0.5f*(px*px+py*py+pz*pz));
                }
                ++p;
            }
        }
    }
    __syncthreads();   // A writes done; wsum free for reuse

    // ---- B phase: full compacted cloud into LDS ----
    unsigned flB = 0; int tsB = 0;
    float dv[16];
    {
        const float* mb = masks + (b*Vv + vB)*Nn + tid*16;
        const float* db = depth + (b*Vv + vB)*Nn + tid*16;
        #pragma unroll
        for (int q = 0; q < 4; ++q){
            float4 m4 = *(const float4*)(mb + q*4);
            float4 d4 = *(const float4*)(db + q*4);
            const float* mv = (const float*)&m4;
            const float* dd = (const float*)&d4;
            #pragma unroll
            for (int r = 0; r < 4; ++r){
                dv[q*4+r] = dd[r];
                if (mv[r] > 0.5f){ flB |= 1u << (q*4 + r); ++tsB; }
            }
        }
    }
    int incB = tsB;
    #pragma unroll
    for (int off = 1; off < 64; off <<= 1){
        int t = __shfl_up(incB, off, 64);
        if (lane >= off) incB += t;
    }
    if (lane == 63) wsum[wv] = incB;
    __syncthreads();
    int baseB = incB - tsB;
    #pragma unroll
    for (int w = 0; w < 4; ++w) if (w < wv) baseB += wsum[w];
    int cntB = wsum[0] + wsum[1] + wsum[2] + wsum[3];

    {
        int p = baseB;
        #pragma unroll
        for (int k = 0; k < 16; ++k){
            if (flB & (1u << k)){
                int n = tid*16 + k;
                float d = dv[k];
                float x = (float)(n & 63), y = (float)(n >> 6);
                float ux = fmaf(MB[0],x, fmaf(MB[1],y, MB[2]));
                float uy = fmaf(MB[3],x, fmaf(MB[4],y, MB[5]));
                float uz = fmaf(MB[6],x, fmaf(MB[7],y, MB[8]));
                float px = fmaf(ux,d,tB[0]), py = fmaf(uy,d,tB[1]), pz = fmaf(uz,d,tB[2]);
                sB[p++] = make_float4(px,py,pz, 0.5f*(px*px+py*py+pz*pz));
            }
        }
    }
    int cntBp = (cntB + 15) & ~15;
    if (tid < cntBp - cntB) sB[cntB + tid] = make_float4(0.f, 0.f, 0.f, PADW);
    __syncthreads();

    // ---- pair loop: 32 rowgrps (4 rows) x 8 colparts ----
    int rowgrp = tid >> 3, colpart = tid & 7;
    int rbase = rowgrp * 4;
    float4 a0 = sA[rbase+0], a1 = sA[rbase+1], a2 = sA[rbase+2], a3 = sA[rbase+3];
    float m0 = -3.0e38f, m1 = -3.0e38f, m2 = -3.0e38f, m3 = -3.0e38f;

    int nIter = cntBp >> 4;
    const float4* sbp = sB + colpart;
    #pragma unroll 2
    for (int j = 0; j < nIter; ++j){
        float4 c0 = sbp[16*j];
        float4 c1 = sbp[16*j + 8];
        float u00 = fmaf(a0.z,c0.z, fmaf(a0.y,c0.y, fmaf(a0.x,c0.x, -c0.w)));
        float u01 = fmaf(a0.z,c1.z, fmaf(a0.y,c1.y, fmaf(a0.x,c1.x, -c1.w)));
        float u10 = fmaf(a1.z,c0.z, fmaf(a1.y,c0.y, fmaf(a1.x,c0.x, -c0.w)));
        float u11 = fmaf(a1.z,c1.z, fmaf(a1.y,c1.y, fmaf(a1.x,c1.x, -c1.w)));
        float u20 = fmaf(a2.z,c0.z, fmaf(a2.y,c0.y, fmaf(a2.x,c0.x, -c0.w)));
        float u21 = fmaf(a2.z,c1.z, fmaf(a2.y,c1.y, fmaf(a2.x,c1.x, -c1.w)));
        float u30 = fmaf(a3.z,c0.z, fmaf(a3.y,c0.y, fmaf(a3.x,c0.x, -c0.w)));
        float u31 = fmaf(a3.z,c1.z, fmaf(a3.y,c1.y, fmaf(a3.x,c1.x, -c1.w)));
        m0 = fmaxf(fmaxf(u00, u01), m0);   // v_max3
        m1 = fmaxf(fmaxf(u10, u11), m1);
        m2 = fmaxf(fmaxf(u20, u21), m2);
        m3 = fmaxf(fmaxf(u30, u31), m3);
    }
    // exact per-row max over 8 colparts
    #pragma unroll
    for (int off = 1; off < 8; off <<= 1){
        m0 = fmaxf(m0, __shfl_xor(m0, off, 64));
        m1 = fmaxf(m1, __shfl_xor(m1, off, 64));
        m2 = fmaxf(m2, __shfl_xor(m2, off, 64));
        m3 = fmaxf(m3, __shfl_xor(m3, off, 64));
    }
    if (colpart == 0){
        float s = 0.f;
        if (rbase + 0 < nRows) s += 2.0f*(a0.w - m0);
        if (rbase + 1 < nRows) s += 2.0f*(a1.w - m1);
        if (rbase + 2 < nRows) s += 2.0f*(a2.w - m2);
        if (rbase + 3 < nRows) s += 2.0f*(a3.w - m3);
        sred[rowgrp] = s;
    }
    __syncthreads();
    if (tid < 32){
        float v = sred[tid];
        #pragma unroll
        for (int off = 1; off < 32; off <<= 1) v += __shfl_xor(v, off, 64);
        if (tid == 0) ws[bid] = v / (fmaxf((float)cntA, 1.0f) * 16.0f);
    }
}

// 1 block: fixed-order deterministic sum of 512 partials.
__global__ void __launch_bounds__(256) final_kernel(const float* __restrict__ ws,
                                                    float* __restrict__ out){
    __shared__ float red[4];
    int tid = threadIdx.x;
    float v = ws[tid] + ws[tid + 256];
    for (int off = 32; off > 0; off >>= 1) v += __shfl_down(v, off, 64);
    if ((tid & 63) == 0) red[tid >> 6] = v;
    __syncthreads();
    if (tid == 0) out[0] = red[0] + red[1] + red[2] + red[3];
}

extern "C" void kernel_launch(void* const* d_in, const int* in_sizes, int n_in,
                              void* d_out, int out_size, void* d_ws, size_t ws_size,
                              hipStream_t stream) {
    // inputs: 0 views (unused), 1 poses, 2 masks, 3 intrinsics, 4 depth_maps, 5 num_views
    const float* poses = (const float*)d_in[1];
    const float* masks = (const float*)d_in[2];
    const float* intr  = (const float*)d_in[3];
    const float* depth = (const float*)d_in[4];
    float* ws  = (float*)d_ws;
    float* out = (float*)d_out;

    fused_kernel<<<NBLKS, 256, 0, stream>>>(poses, masks, intr, depth, ws);
    final_kernel<<<1, 256, 0, stream>>>(ws, out);
}

// Round 6
// 24.522 us; speedup vs baseline: 4.7556x; 1.0579x over previous
//
#include <hip/hip_runtime.h>
#include <math.h>

// Problem shape (fixed by setup_inputs)
#define Bb 2
#define Vv 3
#define Nn 4096
#define NDIR 16
#define NRB 32           // rowblocks per dir
#define RPB 128          // rows per block
#define NBLKS (NDIR*NRB) // 512
#define PADW 1.5e38f

// ws (uint view): [0..511] partial bits, [512..1023] ~partial bits (self-validating pairs)

__device__ __forceinline__ void slots_for_dir(int dir, int* sA, int* sB){
    int k = dir & 3, bi = dir >> 2, b = bi >> 1;
    switch (k){
        case 0:  *sA = b;       *sB = 6 + bi;  break;  // fwd d_ab: rows ref, cols p2r
        case 1:  *sA = 6 + bi;  *sB = b;       break;  // fwd d_ba
        case 2:  *sA = 2 + bi;  *sB = 10 + bi; break;  // bwd d_ab: rows tgt, cols r2t
        default: *sA = 10 + bi; *sB = 2 + bi;  break;  // bwd d_ba
    }
}

// slot -> (b, view for depth/mask, M[9], tv[3]) ; point = M*(x,y,1)*d + tv
__device__ __forceinline__ void build_matrix(int slot,
                                             const float* __restrict__ poses,
                                             const float* __restrict__ intr,
                                             float* M, float* tv, int* bOut, int* vOut){
    int type, b, im1;
    if (slot < 2)      { type = 0; b = slot;         im1 = 0; }
    else if (slot < 6) { type = 1; b = (slot-2)>>1;  im1 = (slot-2)&1; }
    else if (slot < 10){ type = 2; b = (slot-6)>>1;  im1 = (slot-6)&1; }
    else               { type = 3; b = (slot-10)>>1; im1 = (slot-10)&1; }
    int vi = im1 + 1;
    *bOut = b;
    *vOut = (type==0 || type==3) ? 0 : vi;

    const float* Km = intr + b*9;
    float ka=Km[0],kb=Km[1],kc=Km[2],kd=Km[3],ke=Km[4],kf=Km[5],kg=Km[6],kh=Km[7],ki=Km[8];
    float c00=(ke*ki-kf*kh), c10=-(kd*ki-kf*kg), c20=(kd*kh-ke*kg);
    float det = ka*c00 + kb*c10 + kc*c20, iv = 1.0f/det;
    float Ki[9] = { c00*iv, -(kb*ki-kc*kh)*iv,  (kb*kf-kc*ke)*iv,
                    c10*iv,  (ka*ki-kc*kg)*iv, -(ka*kf-kc*kd)*iv,
                    c20*iv, -(ka*kh-kb*kg)*iv,  (ka*ke-kb*kd)*iv };
    tv[0] = tv[1] = tv[2] = 0.f;
    if (type < 2){
        #pragma unroll
        for (int i = 0; i < 9; ++i) M[i] = Ki[i];
        return;
    }
    const float* P0 = poses + (b*Vv + 0)*16;
    const float* Pi = poses + (b*Vv + vi)*16;
    float R[9];
    if (type == 2){  // inv(pose0) @ pose_i
        #pragma unroll
        for (int r = 0; r < 3; ++r){
            #pragma unroll
            for (int c = 0; c < 3; ++c)
                R[r*3+c] = P0[0*4+r]*Pi[0*4+c] + P0[1*4+r]*Pi[1*4+c] + P0[2*4+r]*Pi[2*4+c];
            tv[r] = P0[0*4+r]*(Pi[3]-P0[3]) + P0[1*4+r]*(Pi[7]-P0[7]) + P0[2*4+r]*(Pi[11]-P0[11]);
        }
    } else {         // inv(pose_i) @ pose0
        #pragma unroll
        for (int r = 0; r < 3; ++r){
            #pragma unroll
            for (int c = 0; c < 3; ++c)
                R[r*3+c] = Pi[0*4+r]*P0[0*4+c] + Pi[1*4+r]*P0[1*4+c] + Pi[2*4+r]*P0[2*4+c];
            tv[r] = Pi[0*4+r]*(P0[3]-Pi[3]) + Pi[1*4+r]*(P0[7]-Pi[7]) + Pi[2*4+r]*(P0[11]-Pi[11]);
        }
    }
    #pragma unroll
    for (int r = 0; r < 3; ++r)
        #pragma unroll
        for (int c = 0; c < 3; ++c)
            M[r*3+c] = R[r*3+0]*Ki[0*3+c] + R[r*3+1]*Ki[1*3+c] + R[r*3+2]*Ki[2*3+c];
}

// Single fused kernel. Each block builds its A-row slice + full compacted B cloud
// in LDS, computes exact row-mins, publishes a self-validating (bits,~bits) pair.
// Block 0 then spins (coherent reads) until all pairs are consistent and does the
// fixed-order deterministic 512-way sum -> out[0].
__global__ void __launch_bounds__(256) fused_kernel(const float* __restrict__ poses,
                                                    const float* __restrict__ masks,
                                                    const float* __restrict__ intr,
                                                    const float* __restrict__ depth,
                                                    float* __restrict__ ws,
                                                    float* __restrict__ out){
    __shared__ float4 sB[Nn + 16];   // 65792 B
    __shared__ float4 sA[RPB];       // 2048 B
    __shared__ int   wsum[4];
    __shared__ float sred[32];

    int bid = blockIdx.x;
    int rowblk = bid & (NRB-1);
    int dir    = bid >> 5;
    int slotA, slotB;
    slots_for_dir(dir, &slotA, &slotB);

    int tid = threadIdx.x;
    int lane = tid & 63, wv = tid >> 6;

    float MA[9], tA[3], MB[9], tB[3];
    int b, vA, vB, bdummy;
    build_matrix(slotA, poses, intr, MA, tA, &b, &vA);
    build_matrix(slotB, poses, intr, MB, tB, &bdummy, &vB);

    // ---- A phase: mask scan for cntA and this block's row slice ----
    unsigned flA = 0; int tsA = 0;
    {
        const float* mb = masks + (b*Vv + vA)*Nn + tid*16;
        #pragma unroll
        for (int q = 0; q < 4; ++q){
            float4 m4 = *(const float4*)(mb + q*4);
            const float* mv = (const float*)&m4;
            #pragma unroll
            for (int r = 0; r < 4; ++r)
                if (mv[r] > 0.5f){ flA |= 1u << (q*4 + r); ++tsA; }
        }
    }
    int inc = tsA;
    #pragma unroll
    for (int off = 1; off < 64; off <<= 1){
        int t = __shfl_up(inc, off, 64);
        if (lane >= off) inc += t;
    }
    if (lane == 63) wsum[wv] = inc;
    __syncthreads();
    int base = inc - tsA;
    #pragma unroll
    for (int w = 0; w < 4; ++w) if (w < wv) base += wsum[w];
    int cntA = wsum[0] + wsum[1] + wsum[2] + wsum[3];

    int lo = rowblk * RPB;
    int nRows = min(cntA - lo, RPB);
    float partial = 0.f;

    if (nRows > 0){
        // write A slice points
        {
            const float* dbase = depth + (b*Vv + vA)*Nn;
            int p = base;
            #pragma unroll
            for (int k = 0; k < 16; ++k){
                if (flA & (1u << k)){
                    int rel = p - lo;
                    if (rel >= 0 && rel < RPB){
                        int n = tid*16 + k;
                        float d = dbase[n];
                        float x = (float)(n & 63), y = (float)(n >> 6);
                        float ux = fmaf(MA[0],x, fmaf(MA[1],y, MA[2]));
                        float uy = fmaf(MA[3],x, fmaf(MA[4],y, MA[5]));
                        float uz = fmaf(MA[6],x, fmaf(MA[7],y, MA[8]));
                        float px = fmaf(ux,d,tA[0]), py = fmaf(uy,d,tA[1]), pz = fmaf(uz,d,tA[2]);
                        sA[rel] = make_float4(px,py,pz, 0.5f*(px*px+py*py+pz*pz));
                    }
                    ++p;
                }
            }
        }
        __syncthreads();   // A writes done; wsum free for reuse

        // ---- B phase: full compacted cloud into LDS ----
        unsigned flB = 0; int tsB = 0;
        float dv[16];
        {
            const float* mb = masks + (b*Vv + vB)*Nn + tid*16;
            const float* db = depth + (b*Vv + vB)*Nn + tid*16;
            #pragma unroll
            for (int q = 0; q < 4; ++q){
                float4 m4 = *(const float4*)(mb + q*4);
                float4 d4 = *(const float4*)(db + q*4);
                const float* mv = (const float*)&m4;
                const float* dd = (const float*)&d4;
                #pragma unroll
                for (int r = 0; r < 4; ++r){
                    dv[q*4+r] = dd[r];
                    if (mv[r] > 0.5f){ flB |= 1u << (q*4 + r); ++tsB; }
                }
            }
        }
        int incB = tsB;
        #pragma unroll
        for (int off = 1; off < 64; off <<= 1){
            int t = __shfl_up(incB, off, 64);
            if (lane >= off) incB += t;
        }
        if (lane == 63) wsum[wv] = incB;
        __syncthreads();
        int baseB = incB - tsB;
        #pragma unroll
        for (int w = 0; w < 4; ++w) if (w < wv) baseB += wsum[w];
        int cntB = wsum[0] + wsum[1] + wsum[2] + wsum[3];

        {
            int p = baseB;
            #pragma unroll
            for (int k = 0; k < 16; ++k){
                if (flB & (1u << k)){
                    int n = tid*16 + k;
                    float d = dv[k];
                    float x = (float)(n & 63), y = (float)(n >> 6);
                    float ux = fmaf(MB[0],x, fmaf(MB[1],y, MB[2]));
                    float uy = fmaf(MB[3],x, fmaf(MB[4],y, MB[5]));
                    float uz = fmaf(MB[6],x, fmaf(MB[7],y, MB[8]));
                    float px = fmaf(ux,d,tB[0]), py = fmaf(uy,d,tB[1]), pz = fmaf(uz,d,tB[2]);
                    sB[p++] = make_float4(px,py,pz, 0.5f*(px*px+py*py+pz*pz));
                }
            }
        }
        int cntBp = (cntB + 15) & ~15;
        if (tid < cntBp - cntB) sB[cntB + tid] = make_float4(0.f, 0.f, 0.f, PADW);
        __syncthreads();

        // ---- pair loop: 32 rowgrps (4 rows) x 8 colparts ----
        int rowgrp = tid >> 3, colpart = tid & 7;
        int rbase = rowgrp * 4;
        float4 a0 = sA[rbase+0], a1 = sA[rbase+1], a2 = sA[rbase+2], a3 = sA[rbase+3];
        float m0 = -3.0e38f, m1 = -3.0e38f, m2 = -3.0e38f, m3 = -3.0e38f;

        int nIter = cntBp >> 4;
        const float4* sbp = sB + colpart;
        #pragma unroll 2
        for (int j = 0; j < nIter; ++j){
            float4 c0 = sbp[16*j];
            float4 c1 = sbp[16*j + 8];
            float u00 = fmaf(a0.z,c0.z, fmaf(a0.y,c0.y, fmaf(a0.x,c0.x, -c0.w)));
            float u01 = fmaf(a0.z,c1.z, fmaf(a0.y,c1.y, fmaf(a0.x,c1.x, -c1.w)));
            float u10 = fmaf(a1.z,c0.z, fmaf(a1.y,c0.y, fmaf(a1.x,c0.x, -c0.w)));
            float u11 = fmaf(a1.z,c1.z, fmaf(a1.y,c1.y, fmaf(a1.x,c1.x, -c1.w)));
            float u20 = fmaf(a2.z,c0.z, fmaf(a2.y,c0.y, fmaf(a2.x,c0.x, -c0.w)));
            float u21 = fmaf(a2.z,c1.z, fmaf(a2.y,c1.y, fmaf(a2.x,c1.x, -c1.w)));
            float u30 = fmaf(a3.z,c0.z, fmaf(a3.y,c0.y, fmaf(a3.x,c0.x, -c0.w)));
            float u31 = fmaf(a3.z,c1.z, fmaf(a3.y,c1.y, fmaf(a3.x,c1.x, -c1.w)));
            m0 = fmaxf(fmaxf(u00, u01), m0);   // v_max3
            m1 = fmaxf(fmaxf(u10, u11), m1);
            m2 = fmaxf(fmaxf(u20, u21), m2);
            m3 = fmaxf(fmaxf(u30, u31), m3);
        }
        #pragma unroll
        for (int off = 1; off < 8; off <<= 1){
            m0 = fmaxf(m0, __shfl_xor(m0, off, 64));
            m1 = fmaxf(m1, __shfl_xor(m1, off, 64));
            m2 = fmaxf(m2, __shfl_xor(m2, off, 64));
            m3 = fmaxf(m3, __shfl_xor(m3, off, 64));
        }
        if (colpart == 0){
            float s = 0.f;
            if (rbase + 0 < nRows) s += 2.0f*(a0.w - m0);
            if (rbase + 1 < nRows) s += 2.0f*(a1.w - m1);
            if (rbase + 2 < nRows) s += 2.0f*(a2.w - m2);
            if (rbase + 3 < nRows) s += 2.0f*(a3.w - m3);
            sred[rowgrp] = s;
        }
        __syncthreads();
        if (tid == 0){
            float tsum = 0.f;
            #pragma unroll
            for (int g = 0; g < 16; ++g) tsum += sred[g] + sred[g+16];
            partial = tsum / (fmaxf((float)cntA, 1.0f) * 16.0f);
        }
    }

    // ---- publish self-validating pair (bits, ~bits) ----
    unsigned* wsu = (unsigned*)ws;
    if (tid == 0){
        unsigned pb = __float_as_uint(partial);
        atomicExch(&wsu[bid], pb);
        atomicExch(&wsu[NBLKS + bid], ~pb);
    }
    if (bid != 0) return;

    // ---- block 0: wait for all 512 consistent pairs, fixed-order sum ----
    __syncthreads();   // sred reuse safety
    float p0, p1;
    {
        unsigned va, vb;
        for (;;){
            va = atomicAdd(&wsu[tid], 0u);
            vb = atomicAdd(&wsu[NBLKS + tid], 0u);
            if (va == ~vb) break;
            __builtin_amdgcn_s_sleep(1);
        }
        p0 = __uint_as_float(va);
        for (;;){
            va = atomicAdd(&wsu[tid + 256], 0u);
            vb = atomicAdd(&wsu[NBLKS + tid + 256], 0u);
            if (va == ~vb) break;
            __builtin_amdgcn_s_sleep(1);
        }
        p1 = __uint_as_float(va);
    }
    float v = p0 + p1;
    for (int off = 32; off > 0; off >>= 1) v += __shfl_down(v, off, 64);
    if (lane == 0) sred[wv] = v;
    __syncthreads();
    if (tid == 0) out[0] = sred[0] + sred[1] + sred[2] + sred[3];
}

extern "C" void kernel_launch(void* const* d_in, const int* in_sizes, int n_in,
                              void* d_out, int out_size, void* d_ws, size_t ws_size,
                              hipStream_t stream) {
    // inputs: 0 views (unused), 1 poses, 2 masks, 3 intrinsics, 4 depth_maps, 5 num_views
    const float* poses = (const float*)d_in[1];
    const float* masks = (const float*)d_in[2];
    const float* intr  = (const float*)d_in[3];
    const float* depth = (const float*)d_in[4];
    float* ws  = (float*)d_ws;
    float* out = (float*)d_out;

    fused_kernel<<<NBLKS, 256, 0, stream>>>(poses, masks, intr, depth, ws, out);
}